// Round 6
// baseline (407.276 us; speedup 1.0000x reference)
//
#include <hip/hip_runtime.h>
#include <cstdint>

#define H_ 128
#define W_ 128
#define HW 16384

typedef _Float16 f16x8 __attribute__((ext_vector_type(8)));
typedef _Float16 f16x4 __attribute__((ext_vector_type(4)));
typedef float f32x4 __attribute__((ext_vector_type(4)));

// ---------------------------------------------------------------------------
// NCHW fp32 -> NHWC fp16 transpose for extra_feat (192 ch). Block = 1 row.
// ---------------------------------------------------------------------------
__global__ __launch_bounds__(256)
void transpose_ef(const float* __restrict__ ef, _Float16* __restrict__ out) {
    __shared__ __align__(16) _Float16 t[128 * 200];
    const int tid = threadIdx.x;
    const int b = blockIdx.x >> 7;
    const int h = blockIdx.x & 127;
    for (int i = tid; i < 192 * 128; i += 256) {
        int c = i >> 7, w = i & 127;
        t[w * 200 + c] = (_Float16)ef[((size_t)(b * 192 + c) * 128 + h) * 128 + w];
    }
    __syncthreads();
    _Float16* ob = out + ((size_t)(b * 128 + h) * 128) * 192;
    for (int i = tid; i < 128 * 24; i += 256) {
        int px = i / 24, c8 = i % 24;
        *(f16x8*)(ob + px * 192 + c8 * 8) = *(const f16x8*)(t + px * 200 + c8 * 8);
    }
}

// ---------------------------------------------------------------------------
// x NCHW fp32 -> xt[b][g][px][c8] fp16 (16B chunk per (px,g)).
// ---------------------------------------------------------------------------
__global__ __launch_bounds__(256)
void transpose_x(const float* __restrict__ x, _Float16* __restrict__ xt) {
    int i = blockIdx.x * 256 + threadIdx.x;
    int px = i & 16383;
    int g  = (i >> 14) & 15;
    int b  = i >> 18;
    const float* xp = x + ((size_t)(b * 128 + g * 8) * HW) + px;
    f16x8 v;
    #pragma unroll
    for (int c = 0; c < 8; ++c) v[c] = (_Float16)xp[c * HW];
    *(f16x8*)(xt + (size_t)i * 8) = v;
}

// ---------------------------------------------------------------------------
// conv weight (COUT,CIN,3,3) fp32 -> A layout fp16.
// ---------------------------------------------------------------------------
__global__ void prep_convA(const float* __restrict__ w, _Float16* __restrict__ Ap,
                           int CIN, int COUT, int COpad) {
    int i = blockIdx.x * 256 + threadIdx.x;
    int total = 9 * CIN * COpad;
    if (i >= total) return;
    int kb = i / (COpad * 8);
    int rem = i - kb * (COpad * 8);
    int co = rem >> 3, j = rem & 7;
    int k = kb * 8 + j;
    int s = k / CIN;
    int ci = k - s * CIN;
    int kh = s / 3, kw = s % 3;
    float v = (co < COUT) ? w[((size_t)co * CIN + ci) * 9 + kh * 3 + kw] : 0.f;
    Ap[i] = (_Float16)v;
}

// ---------------------------------------------------------------------------
// MFMA implicit-GEMM 3x3 conv, pad 1. Wave tiling: NWM x NWN waves,
// per wave MT m-tiles (16 co) x NT n-tiles (16 px). NWN*NT*16 == 128.
// m=64/wave -> each bF ds_read feeds MT MFMAs.
// ---------------------------------------------------------------------------
template<int CIN_T, int COpad_T, int NWM, int NWN, int MT, int NT, int ACT>
__global__ __launch_bounds__(256)
void conv_mfma(const _Float16* __restrict__ in, const _Float16* __restrict__ Ap,
               const float* __restrict__ bias, void* __restrict__ outp) {
    static_assert(NWM * NWN == 4 && NWN * NT * 16 == 128, "tiling");
    constexpr int NKH = (CIN_T == 64) ? 3 : 1;
    constexpr int NST = 3 / NKH;
    constexpr int CPC = CIN_T / 8;
    constexpr int TC  = NKH * 130 * CPC;
    __shared__ __align__(16) _Float16 lds[TC * 8];

    const int tid  = threadIdx.x;
    const int b    = blockIdx.x >> 7;
    const int h    = blockIdx.x & 127;
    const int cogB = blockIdx.y * (NWM * MT * 16);
    const int wv   = tid >> 6;
    const int wv_m = wv / NWN;
    const int wv_n = wv % NWN;
    const int lane = tid & 63;
    const int quad = lane >> 4;
    const int l16  = lane & 15;

    f32x4 acc[MT][NT];
    #pragma unroll
    for (int mt = 0; mt < MT; ++mt)
        #pragma unroll
        for (int nt = 0; nt < NT; ++nt) acc[mt][nt] = (f32x4){0.f, 0.f, 0.f, 0.f};

    const _Float16* inb = in + (size_t)b * (HW * CIN_T);

    #pragma unroll 1
    for (int s = 0; s < NST; ++s) {
        __syncthreads();
        for (int i = tid; i < TC; i += 256) {
            int kh_l = i / (130 * CPC);
            int r2   = i - kh_l * (130 * CPC);
            int wp_  = r2 / CPC;
            int c8   = r2 - wp_ * CPC;
            int kh   = s * NKH + kh_l;
            int hh   = h - 1 + kh;
            int w    = wp_ - 1;
            f16x8 v = (f16x8){0, 0, 0, 0, 0, 0, 0, 0};
            if ((unsigned)hh < 128u && (unsigned)w < 128u)
                v = *(const f16x8*)(inb + (hh * 128 + w) * CIN_T + c8 * 8);
            int slot = (c8 & ~7) | ((c8 & 7) ^ (wp_ & 7));
            ((f16x8*)lds)[(kh_l * 130 + wp_) * CPC + slot] = v;
        }
        __syncthreads();
        #pragma unroll
        for (int kh_l = 0; kh_l < NKH; ++kh_l) {
            const int kh = s * NKH + kh_l;
            #pragma unroll
            for (int kwi = 0; kwi < 3; ++kwi) {
                #pragma unroll
                for (int ci32 = 0; ci32 < CIN_T / 32; ++ci32) {
                    const int kb0 = (kh * 3 + kwi) * CPC + ci32 * 4;
                    f16x8 aF[MT];
                    #pragma unroll
                    for (int mt = 0; mt < MT; ++mt) {
                        int co_m = cogB + (wv_m * MT + mt) * 16 + l16;
                        aF[mt] = *(const f16x8*)(Ap + ((size_t)(kb0 + quad) * COpad_T + co_m) * 8);
                    }
                    const int c8v = ci32 * 4 + quad;
                    #pragma unroll
                    for (int nt = 0; nt < NT; ++nt) {
                        int n  = (wv_n * NT + nt) * 16 + l16;
                        int wq = n + kwi;
                        int slot = (c8v & ~7) | ((c8v & 7) ^ (wq & 7));
                        f16x8 bF = ((const f16x8*)lds)[(kh_l * 130 + wq) * CPC + slot];
                        #pragma unroll
                        for (int mt = 0; mt < MT; ++mt)
                            acc[mt][nt] = __builtin_amdgcn_mfma_f32_16x16x32_f16(aF[mt], bF, acc[mt][nt], 0, 0, 0);
                    }
                }
            }
        }
    }

    if (ACT == 1) {
        _Float16* ob = (_Float16*)outp + ((size_t)(b * 128 + h) * 128) * 64;
        #pragma unroll
        for (int mt = 0; mt < MT; ++mt) {
            int co_b = mt * 16 + quad * 4;
            #pragma unroll
            for (int nt = 0; nt < NT; ++nt) {
                int px = (wv_n * NT + nt) * 16 + l16;
                f16x4 sv;
                #pragma unroll
                for (int r = 0; r < 4; ++r) {
                    float v = acc[mt][nt][r] + bias[co_b + r];
                    v = v > 0.f ? v : 0.1f * v;
                    sv[r] = (_Float16)v;
                }
                *(f16x4*)(ob + px * 64 + co_b) = sv;
            }
        }
    } else {
        _Float16* ob = (_Float16*)outp + (size_t)b * 432 * HW + h * 128;
        #pragma unroll
        for (int mt = 0; mt < MT; ++mt) {
            #pragma unroll
            for (int r = 0; r < 4; ++r) {
                int co = cogB + (wv_m * MT + mt) * 16 + quad * 4 + r;
                if (co < 432) {
                    float bv = bias[co];
                    #pragma unroll
                    for (int nt = 0; nt < NT; ++nt) {
                        int px = (wv_n * NT + nt) * 16 + l16;
                        float v = acc[mt][nt][r] + bv;
                        if (co < 288) {
                            float e = __expf(2.f * v);
                            v = 10.f * (1.f - 2.f / (e + 1.f));
                        } else {
                            v = 1.f / (1.f + __expf(-v));
                        }
                        ob[(size_t)co * HW + px] = (_Float16)v;
                    }
                }
            }
        }
    }
}

// ---------------------------------------------------------------------------
// deform weight -> fp16 Wp[g][o][kc96], kc = k*8+c, kc>=72 zero-padded.
// ---------------------------------------------------------------------------
__global__ void prep_wp(const float* __restrict__ wsrc, _Float16* __restrict__ wp) {
    int i = blockIdx.x * 256 + threadIdx.x;
    if (i >= 16 * 64 * 96) return;
    int kc = i % 96;
    int go = i / 96;
    int o  = go & 63;
    int g  = go >> 6;
    float v = 0.f;
    if (kc < 72) {
        int k = kc >> 3, c = kc & 7;
        v = wsrc[(o * 128 + g * 8 + c) * 9 + k];
    }
    wp[i] = (_Float16)v;
}

// ---------------------------------------------------------------------------
// Deformable conv, 4-way group split. V-build swizzle k^(px&15) (bank-clean);
// o4 loads batched ahead of gathers; epilogue transposes acc through LDS for
// coalesced 256B-line fp16 partial stores.
// ---------------------------------------------------------------------------
__global__ __launch_bounds__(256)
void deform_mfma(const _Float16* __restrict__ xt, const _Float16* __restrict__ o4,
                 const _Float16* __restrict__ wp, _Float16* __restrict__ partial) {
    __shared__ __align__(16) char vlds[128 * 256];   // 32 KB
    const int tid  = threadIdx.x;
    const int gq   = blockIdx.x & 3;
    const int bh   = blockIdx.x >> 2;
    const int b    = bh >> 7;
    const int hrow = bh & 127;
    const int wv   = tid >> 6;
    const int lane = tid & 63;
    const int quad = lane >> 4;
    const int l16  = lane & 15;

    const int px = tid & 127;
    const int ks = tid >> 7;           // k parity (wave-uniform)

    {
        f32x4 z = (f32x4){0.f, 0.f, 0.f, 0.f};
        for (int i = tid; i < 2048; i += 256) ((f32x4*)vlds)[i] = z;
    }

    f16x8 aF[4][3];
    #pragma unroll
    for (int gl = 0; gl < 4; ++gl) {
        const _Float16* wg = wp + ((size_t)((gq * 4 + gl) * 64 + wv * 16 + l16)) * 96 + quad * 8;
        #pragma unroll
        for (int s = 0; s < 3; ++s) aF[gl][s] = *(const f16x8*)(wg + s * 32);
    }

    const _Float16* o4p = o4 + (size_t)b * 432 * HW + hrow * W_ + px;

    f32x4 acc[8];
    #pragma unroll
    for (int nt = 0; nt < 8; ++nt) acc[nt] = (f32x4){0.f, 0.f, 0.f, 0.f};

    #pragma unroll 1
    for (int gl = 0; gl < 4; ++gl) {
        const int g = gq * 4 + gl;
        const _Float16* xg = xt + ((size_t)(b * 16 + g) * HW) * 8;
        __syncthreads();
        // batch all offset/mask loads first (MLP), then dependent gathers
        float dyv[5], dxv[5], mv[5];
        #pragma unroll
        for (int ki = 0; ki < 5; ++ki) {
            int k = ks + 2 * ki;
            if (k < 9) {
                dyv[ki] = (float)o4p[(g * 18 + 2 * k) * HW];
                dxv[ki] = (float)o4p[(g * 18 + 2 * k + 1) * HW];
                mv[ki]  = (float)o4p[(288 + g * 9 + k) * HW];
            }
        }
        #pragma unroll
        for (int ki = 0; ki < 5; ++ki) {
            int k = ks + 2 * ki;
            if (k < 9) {
                float py  = (float)(hrow - 1 + k / 3) + dyv[ki];
                float pxf = (float)(px - 1 + k % 3) + dxv[ki];
                float y0f = floorf(py), x0f = floorf(pxf);
                float ly = py - y0f, lx = pxf - x0f;
                int y0 = (int)y0f, x0 = (int)x0f;
                int y1 = y0 + 1,  x1 = x0 + 1;
                float vy0 = ((unsigned)y0 < 128u) ? 1.f : 0.f;
                float vy1 = ((unsigned)y1 < 128u) ? 1.f : 0.f;
                float vx0 = ((unsigned)x0 < 128u) ? 1.f : 0.f;
                float vx1 = ((unsigned)x1 < 128u) ? 1.f : 0.f;
                float m = mv[ki];
                float w00 = (1.f - ly) * (1.f - lx) * vy0 * vx0 * m;
                float w01 = (1.f - ly) * lx         * vy0 * vx1 * m;
                float w10 = ly * (1.f - lx)         * vy1 * vx0 * m;
                float w11 = ly * lx                 * vy1 * vx1 * m;
                int yc0 = min(max(y0, 0), 127), yc1 = min(max(y1, 0), 127);
                int xc0 = min(max(x0, 0), 127), xc1 = min(max(x1, 0), 127);
                f16x8 c00 = *(const f16x8*)(xg + (yc0 * W_ + xc0) * 8);
                f16x8 c01 = *(const f16x8*)(xg + (yc0 * W_ + xc1) * 8);
                f16x8 c10 = *(const f16x8*)(xg + (yc1 * W_ + xc0) * 8);
                f16x8 c11 = *(const f16x8*)(xg + (yc1 * W_ + xc1) * 8);
                f16x8 vv;
                #pragma unroll
                for (int c = 0; c < 8; ++c) {
                    float s = w00 * (float)c00[c] + w01 * (float)c01[c]
                            + w10 * (float)c10[c] + w11 * (float)c11[c];
                    vv[c] = (_Float16)s;
                }
                int chunk = k ^ (px & 15);
                *(f16x8*)(vlds + px * 256 + chunk * 16) = vv;
            }
        }
        __syncthreads();
        #pragma unroll
        for (int nt = 0; nt < 8; ++nt) {
            int row = nt * 16 + l16;
            int sw  = row & 15;
            #pragma unroll
            for (int s = 0; s < 3; ++s) {
                f16x8 bF = *(const f16x8*)(vlds + row * 256 + (((s << 2) + quad) ^ sw) * 16);
                acc[nt] = __builtin_amdgcn_mfma_f32_16x16x32_f16(aF[gl][s], bF, acc[nt], 0, 0, 0);
            }
        }
    }

    // ---- epilogue: transpose acc through LDS, coalesced fp16 stores ----
    __syncthreads();
    float* vf = (float*)vlds;
    #pragma unroll
    for (int r = 0; r < 4; ++r) {
        int o = wv * 16 + quad * 4 + r;
        int key = (o >> 2) & 7;
        #pragma unroll
        for (int nt = 0; nt < 8; ++nt) {
            int col = nt ^ key;
            vf[o * 128 + col * 16 + l16] = acc[nt][r];
        }
    }
    __syncthreads();
    _Float16* pb = partial + (((size_t)gq * 4 + b) * 64) * HW + hrow * W_;
    #pragma unroll
    for (int it = 0; it < 8; ++it) {
        int idx = tid + it * 256;
        int o   = idx >> 5;
        int c4  = idx & 31;
        int col = (c4 >> 2) ^ ((o >> 2) & 7);
        f32x4 v = *(const f32x4*)(vf + o * 128 + col * 16 + (c4 & 3) * 4);
        f16x4 hv;
        #pragma unroll
        for (int j = 0; j < 4; ++j) hv[j] = (_Float16)v[j];
        *(f16x4*)(pb + (size_t)o * HW + c4 * 4) = hv;
    }
}

// ---------------------------------------------------------------------------
// out = bias + sum of 4 fp16 partials. 8 elems/thread.
// ---------------------------------------------------------------------------
__global__ __launch_bounds__(256)
void reduce_out(const _Float16* __restrict__ p, const float* __restrict__ bias,
                float* __restrict__ out) {
    const int i8 = (blockIdx.x * 256 + threadIdx.x) * 8;
    const int o  = (i8 >> 14) & 63;
    const float bv = bias[o];
    f16x8 a = *(const f16x8*)(p + i8);
    f16x8 b = *(const f16x8*)(p + i8 + 4194304);
    f16x8 c = *(const f16x8*)(p + i8 + 8388608);
    f16x8 d = *(const f16x8*)(p + i8 + 12582912);
    float t[8];
    #pragma unroll
    for (int j = 0; j < 8; ++j)
        t[j] = bv + (float)a[j] + (float)b[j] + (float)c[j] + (float)d[j];
    *(float4*)(out + i8)     = make_float4(t[0], t[1], t[2], t[3]);
    *(float4*)(out + i8 + 4) = make_float4(t[4], t[5], t[6], t[7]);
}

// ---------------------------------------------------------------------------
extern "C" void kernel_launch(void* const* d_in, const int* in_sizes, int n_in,
                              void* d_out, int out_size, void* d_ws, size_t ws_size,
                              hipStream_t stream) {
    const float* x  = (const float*)d_in[0];
    const float* ef = (const float*)d_in[1];
    const float* w1 = (const float*)d_in[2];
    const float* b1 = (const float*)d_in[3];
    const float* w2 = (const float*)d_in[4];
    const float* b2 = (const float*)d_in[5];
    const float* w3 = (const float*)d_in[6];
    const float* b3 = (const float*)d_in[7];
    const float* w4 = (const float*)d_in[8];
    const float* b4 = (const float*)d_in[9];
    const float* wd = (const float*)d_in[10];
    const float* bd = (const float*)d_in[11];
    float* out = (float*)d_out;

    char* ws = (char*)d_ws;
    _Float16* ef_t = (_Float16*)(ws);                     // 25,165,824 B
    _Float16* part = (_Float16*)(ws);                     // 33,554,432 B (deform phase, overlays ef_t+tA)
    _Float16* tA   = (_Float16*)(ws + 25165824);          //  8,388,608 B
    _Float16* tB   = (_Float16*)(ws + 33554432);          //  8,388,608 B
    _Float16* o4h  = (_Float16*)(ws + 41943040);          // 56,623,104 B
    _Float16* wpd  = (_Float16*)(ws + 98566144);          //    196,608 B
    _Float16* A1   = (_Float16*)(ws + 98762752);          //    221,184 B
    _Float16* A2   = (_Float16*)(ws + 98983936);          //     73,728 B
    _Float16* A3   = (_Float16*)(ws + 99057664);          //     73,728 B
    _Float16* A4   = (_Float16*)(ws + 99131392);          //    589,824 B (COpad 512)
    _Float16* xtb  = (_Float16*)(ws + 99721216);          // 16,777,216 B -> ends 116,498,432

    prep_wp<<<384, 256, 0, stream>>>(wd, wpd);
    prep_convA<<<432, 256, 0, stream>>>(w1, A1, 192, 64, 64);
    prep_convA<<<144, 256, 0, stream>>>(w2, A2, 64, 64, 64);
    prep_convA<<<144, 256, 0, stream>>>(w3, A3, 64, 64, 64);
    prep_convA<<<1152, 256, 0, stream>>>(w4, A4, 64, 432, 512);
    transpose_x<<<4096, 256, 0, stream>>>(x, xtb);
    transpose_ef<<<512, 256, 0, stream>>>(ef, ef_t);

    conv_mfma<192, 64, 1, 4, 4, 2, 1><<<dim3(512, 1), 256, 0, stream>>>(ef_t, A1, b1, tA);
    conv_mfma< 64, 64, 1, 4, 4, 2, 1><<<dim3(512, 1), 256, 0, stream>>>(tA, A2, b2, tB);
    conv_mfma< 64, 64, 1, 4, 4, 2, 1><<<dim3(512, 1), 256, 0, stream>>>(tB, A3, b3, tA);
    conv_mfma< 64, 512, 2, 2, 4, 4, 2><<<dim3(512, 4), 256, 0, stream>>>(tA, A4, b4, o4h);

    deform_mfma<<<2048, 256, 0, stream>>>(xtb, o4h, wpd, part);
    reduce_out<<<2048, 256, 0, stream>>>(part, bd, out);
}

// Round 7
// 397.513 us; speedup vs baseline: 1.0246x; 1.0246x over previous
//
#include <hip/hip_runtime.h>
#include <cstdint>

#define H_ 128
#define W_ 128
#define HW 16384

typedef _Float16 f16x8 __attribute__((ext_vector_type(8)));
typedef _Float16 f16x4 __attribute__((ext_vector_type(4)));
typedef _Float16 f16x2 __attribute__((ext_vector_type(2)));
typedef float f32x4 __attribute__((ext_vector_type(4)));

// ---------------------------------------------------------------------------
// All weight preps + input transposes in ONE launch (branch ladder on blockIdx).
// ---------------------------------------------------------------------------
__global__ __launch_bounds__(256)
void prep_all(const float* __restrict__ wd, const float* __restrict__ w1,
              const float* __restrict__ w2, const float* __restrict__ w3,
              const float* __restrict__ w4, const float* __restrict__ x,
              const float* __restrict__ ef,
              _Float16* __restrict__ wp, _Float16* __restrict__ A1,
              _Float16* __restrict__ A2, _Float16* __restrict__ A3,
              _Float16* __restrict__ A4, _Float16* __restrict__ xt,
              _Float16* __restrict__ ef_t) {
    __shared__ __align__(16) _Float16 t[128 * 200];
    const int bx  = blockIdx.x;
    const int tid = threadIdx.x;
    if (bx < 384) {                          // deform weight -> Wp[g][o][kc96]
        int i = bx * 256 + tid;
        int kc = i % 96;
        int go = i / 96;
        int o = go & 63, g = go >> 6;
        float v = 0.f;
        if (kc < 72) { int k = kc >> 3, c = kc & 7; v = wd[(o * 128 + g * 8 + c) * 9 + k]; }
        wp[i] = (_Float16)v;
    } else if (bx < 2256) {                  // conv A layouts
        const float* w; _Float16* Ap; int CIN, COUT, COpad, base;
        if (bx < 816)       { w = w1; Ap = A1; CIN = 192; COUT = 64;  COpad = 64;  base = 384; }
        else if (bx < 960)  { w = w2; Ap = A2; CIN = 64;  COUT = 64;  COpad = 64;  base = 816; }
        else if (bx < 1104) { w = w3; Ap = A3; CIN = 64;  COUT = 64;  COpad = 64;  base = 960; }
        else                { w = w4; Ap = A4; CIN = 64;  COUT = 432; COpad = 512; base = 1104; }
        int i = (bx - base) * 256 + tid;
        int kb = i / (COpad * 8);
        int rem = i - kb * (COpad * 8);
        int co = rem >> 3, j = rem & 7;
        int k = kb * 8 + j;
        int s = k / CIN;
        int ci = k - s * CIN;
        int kh = s / 3, kw = s % 3;
        float v = (co < COUT) ? w[((size_t)co * CIN + ci) * 9 + kh * 3 + kw] : 0.f;
        Ap[i] = (_Float16)v;
    } else if (bx < 6352) {                  // x -> xt[b][g][px][c8] fp16
        int i = (bx - 2256) * 256 + tid;
        int px = i & 16383;
        int g  = (i >> 14) & 15;
        int b  = i >> 18;
        const float* xp = x + ((size_t)(b * 128 + g * 8) * HW) + px;
        f16x8 v;
        #pragma unroll
        for (int c = 0; c < 8; ++c) v[c] = (_Float16)xp[c * HW];
        *(f16x8*)(xt + (size_t)i * 8) = v;
    } else {                                 // extra_feat NCHW -> NHWC fp16
        int bb = bx - 6352;
        int b = bb >> 7, h = bb & 127;
        for (int i = tid; i < 192 * 128; i += 256) {
            int c = i >> 7, w = i & 127;
            t[w * 200 + c] = (_Float16)ef[((size_t)(b * 192 + c) * 128 + h) * 128 + w];
        }
        __syncthreads();
        _Float16* ob = ef_t + ((size_t)(b * 128 + h) * 128) * 192;
        for (int i = tid; i < 128 * 24; i += 256) {
            int px = i / 24, c8 = i % 24;
            *(f16x8*)(ob + px * 192 + c8 * 8) = *(const f16x8*)(t + px * 200 + c8 * 8);
        }
    }
}

// ---------------------------------------------------------------------------
// MFMA implicit-GEMM 3x3 conv, pad 1. NWM x NWN waves, MT x NT tiles/wave.
// ACT 1 = lrelu -> NHWC fp16. ACT 2 = conv4 epilogue: offsets 10*tanh packed
// as f16x2 (dy,dx) into off2[b][g][k][px], mask sigmoid into msk[b][g][k][px].
// ---------------------------------------------------------------------------
template<int CIN_T, int COpad_T, int NWM, int NWN, int MT, int NT, int ACT>
__global__ __launch_bounds__(256)
void conv_mfma(const _Float16* __restrict__ in, const _Float16* __restrict__ Ap,
               const float* __restrict__ bias, void* __restrict__ outp,
               _Float16* __restrict__ mskp) {
    static_assert(NWM * NWN == 4 && NWN * NT * 16 == 128, "tiling");
    constexpr int NKH = (CIN_T == 64) ? 3 : 1;
    constexpr int NST = 3 / NKH;
    constexpr int CPC = CIN_T / 8;
    constexpr int TC  = NKH * 130 * CPC;
    __shared__ __align__(16) _Float16 lds[TC * 8];

    const int tid  = threadIdx.x;
    const int b    = blockIdx.x >> 7;
    const int h    = blockIdx.x & 127;
    const int cogB = blockIdx.y * (NWM * MT * 16);
    const int wv   = tid >> 6;
    const int wv_m = wv / NWN;
    const int wv_n = wv % NWN;
    const int lane = tid & 63;
    const int quad = lane >> 4;
    const int l16  = lane & 15;

    f32x4 acc[MT][NT];
    #pragma unroll
    for (int mt = 0; mt < MT; ++mt)
        #pragma unroll
        for (int nt = 0; nt < NT; ++nt) acc[mt][nt] = (f32x4){0.f, 0.f, 0.f, 0.f};

    const _Float16* inb = in + (size_t)b * (HW * CIN_T);

    #pragma unroll 1
    for (int s = 0; s < NST; ++s) {
        __syncthreads();
        for (int i = tid; i < TC; i += 256) {
            int kh_l = i / (130 * CPC);
            int r2   = i - kh_l * (130 * CPC);
            int wp_  = r2 / CPC;
            int c8   = r2 - wp_ * CPC;
            int kh   = s * NKH + kh_l;
            int hh   = h - 1 + kh;
            int w    = wp_ - 1;
            f16x8 v = (f16x8){0, 0, 0, 0, 0, 0, 0, 0};
            if ((unsigned)hh < 128u && (unsigned)w < 128u)
                v = *(const f16x8*)(inb + (hh * 128 + w) * CIN_T + c8 * 8);
            int slot = (c8 & ~7) | ((c8 & 7) ^ (wp_ & 7));
            ((f16x8*)lds)[(kh_l * 130 + wp_) * CPC + slot] = v;
        }
        __syncthreads();
        #pragma unroll
        for (int kh_l = 0; kh_l < NKH; ++kh_l) {
            const int kh = s * NKH + kh_l;
            #pragma unroll
            for (int kwi = 0; kwi < 3; ++kwi) {
                #pragma unroll
                for (int ci32 = 0; ci32 < CIN_T / 32; ++ci32) {
                    const int kb0 = (kh * 3 + kwi) * CPC + ci32 * 4;
                    f16x8 aF[MT];
                    #pragma unroll
                    for (int mt = 0; mt < MT; ++mt) {
                        int co_m = cogB + (wv_m * MT + mt) * 16 + l16;
                        aF[mt] = *(const f16x8*)(Ap + ((size_t)(kb0 + quad) * COpad_T + co_m) * 8);
                    }
                    const int c8v = ci32 * 4 + quad;
                    #pragma unroll
                    for (int nt = 0; nt < NT; ++nt) {
                        int n  = (wv_n * NT + nt) * 16 + l16;
                        int wq = n + kwi;
                        int slot = (c8v & ~7) | ((c8v & 7) ^ (wq & 7));
                        f16x8 bF = ((const f16x8*)lds)[(kh_l * 130 + wq) * CPC + slot];
                        #pragma unroll
                        for (int mt = 0; mt < MT; ++mt)
                            acc[mt][nt] = __builtin_amdgcn_mfma_f32_16x16x32_f16(aF[mt], bF, acc[mt][nt], 0, 0, 0);
                    }
                }
            }
        }
    }

    if (ACT == 1) {
        _Float16* ob = (_Float16*)outp + ((size_t)(b * 128 + h) * 128) * 64;
        #pragma unroll
        for (int mt = 0; mt < MT; ++mt) {
            int co_b = (wv_m * MT + mt) * 16 + quad * 4;
            #pragma unroll
            for (int nt = 0; nt < NT; ++nt) {
                int px = (wv_n * NT + nt) * 16 + l16;
                f16x4 sv;
                #pragma unroll
                for (int r = 0; r < 4; ++r) {
                    float v = acc[mt][nt][r] + bias[co_b + r];
                    v = v > 0.f ? v : 0.1f * v;
                    sv[r] = (_Float16)v;
                }
                *(f16x4*)(ob + px * 64 + co_b) = sv;
            }
        }
    } else {
        _Float16* off2 = (_Float16*)outp;
        #pragma unroll
        for (int mt = 0; mt < MT; ++mt) {
            int co_base = cogB + (wv_m * MT + mt) * 16 + quad * 4;   // even
            #pragma unroll
            for (int r2 = 0; r2 < 2; ++r2) {
                int co0 = co_base + 2 * r2;
                if (co0 < 288) {             // offset pair (dy co0, dx co0+1)
                    int g = co0 / 18;
                    int k = (co0 - g * 18) >> 1;
                    float bv0 = bias[co0], bv1 = bias[co0 + 1];
                    #pragma unroll
                    for (int nt = 0; nt < NT; ++nt) {
                        int px = (wv_n * NT + nt) * 16 + l16;
                        float v0 = acc[mt][nt][2 * r2]     + bv0;
                        float v1 = acc[mt][nt][2 * r2 + 1] + bv1;
                        float e0 = __expf(2.f * v0);
                        float e1 = __expf(2.f * v1);
                        f16x2 ov;
                        ov[0] = (_Float16)(10.f * (1.f - 2.f / (e0 + 1.f)));
                        ov[1] = (_Float16)(10.f * (1.f - 2.f / (e1 + 1.f)));
                        *(f16x2*)(off2 + (((size_t)(b * 16 + g) * 9 + k) * HW + h * 128 + px) * 2) = ov;
                    }
                } else if (co0 < 432) {      // two mask channels
                    #pragma unroll
                    for (int j = 0; j < 2; ++j) {
                        int co = co0 + j;
                        int mm = co - 288;
                        int g = mm / 9;
                        int k = mm - g * 9;
                        float bv = bias[co];
                        #pragma unroll
                        for (int nt = 0; nt < NT; ++nt) {
                            int px = (wv_n * NT + nt) * 16 + l16;
                            float v = acc[mt][nt][2 * r2 + j] + bv;
                            v = 1.f / (1.f + __expf(-v));
                            mskp[((size_t)(b * 16 + g) * 9 + k) * HW + h * 128 + px] = (_Float16)v;
                        }
                    }
                }
            }
        }
    }
}

// ---------------------------------------------------------------------------
// Deformable conv. Block = (b, hrow, 64-px half, group-quarter). Grid 4096.
// V tile 64px x 96kc fp16 in 16 KB LDS, swizzle chunk = k^(pxl&15).
// Packed (dy,dx) + mask loads (2/tap), 16B corner gathers, pk-fp16 lerp.
// ---------------------------------------------------------------------------
__global__ __launch_bounds__(256)
void deform_mfma(const _Float16* __restrict__ xt, const _Float16* __restrict__ off2,
                 const _Float16* __restrict__ msk, const _Float16* __restrict__ wp,
                 _Float16* __restrict__ partial) {
    __shared__ __align__(16) char vlds[64 * 256];   // 16 KB
    const int tid  = threadIdx.x;
    const int bx   = blockIdx.x;
    const int gq   = bx & 3;
    const int ns   = (bx >> 2) & 1;
    const int bh   = bx >> 3;
    const int b    = bh >> 7;
    const int hrow = bh & 127;
    const int wv   = tid >> 6;
    const int lane = tid & 63;
    const int quad = lane >> 4;
    const int l16  = lane & 15;

    const int pxl   = tid & 63;        // local px (V row)
    const int kq    = tid >> 6;        // k-quarter (wave-uniform)
    const int wglob = ns * 64 + pxl;
    const int pxg   = hrow * 128 + wglob;

    {
        f32x4 z = (f32x4){0.f, 0.f, 0.f, 0.f};
        for (int i = tid; i < 1024; i += 256) ((f32x4*)vlds)[i] = z;
    }

    f16x8 aF[4][3];
    #pragma unroll
    for (int gl = 0; gl < 4; ++gl) {
        const _Float16* wg = wp + ((size_t)((gq * 4 + gl) * 64 + wv * 16 + l16)) * 96 + quad * 8;
        #pragma unroll
        for (int s = 0; s < 3; ++s) aF[gl][s] = *(const f16x8*)(wg + s * 32);
    }

    const _Float16* o2b = off2 + (size_t)b * 16 * 9 * HW * 2;
    const _Float16* mb  = msk  + (size_t)b * 16 * 9 * HW;

    f32x4 acc[4];
    #pragma unroll
    for (int nt = 0; nt < 4; ++nt) acc[nt] = (f32x4){0.f, 0.f, 0.f, 0.f};

    #pragma unroll 1
    for (int gl = 0; gl < 4; ++gl) {
        const int g = gq * 4 + gl;
        const _Float16* xg = xt + ((size_t)(b * 16 + g) * HW) * 8;
        __syncthreads();
        // batched loads: up to 3 taps (k = kq, kq+4, kq+8), wave-uniform count
        float dyv[3], dxv[3], mv[3];
        #pragma unroll
        for (int i = 0; i < 3; ++i) {
            int k = kq + 4 * i;
            if (k < 9) {
                f16x2 od = *(const f16x2*)(o2b + ((size_t)(g * 9 + k) * HW + pxg) * 2);
                dyv[i] = (float)od[0];
                dxv[i] = (float)od[1];
                mv[i]  = (float)mb[(size_t)(g * 9 + k) * HW + pxg];
            }
        }
        #pragma unroll
        for (int i = 0; i < 3; ++i) {
            int k = kq + 4 * i;
            if (k < 9) {
                float py  = (float)(hrow - 1 + k / 3) + dyv[i];
                float pxf = (float)(wglob - 1 + k % 3) + dxv[i];
                float y0f = floorf(py), x0f = floorf(pxf);
                float ly = py - y0f, lx = pxf - x0f;
                int y0 = (int)y0f, x0 = (int)x0f;
                int y1 = y0 + 1,  x1 = x0 + 1;
                float vy0 = ((unsigned)y0 < 128u) ? 1.f : 0.f;
                float vy1 = ((unsigned)y1 < 128u) ? 1.f : 0.f;
                float vx0 = ((unsigned)x0 < 128u) ? 1.f : 0.f;
                float vx1 = ((unsigned)x1 < 128u) ? 1.f : 0.f;
                float m = mv[i];
                float w00 = (1.f - ly) * (1.f - lx) * vy0 * vx0 * m;
                float w01 = (1.f - ly) * lx         * vy0 * vx1 * m;
                float w10 = ly * (1.f - lx)         * vy1 * vx0 * m;
                float w11 = ly * lx                 * vy1 * vx1 * m;
                int yc0 = min(max(y0, 0), 127), yc1 = min(max(y1, 0), 127);
                int xc0 = min(max(x0, 0), 127), xc1 = min(max(x1, 0), 127);
                f16x8 c00 = *(const f16x8*)(xg + (yc0 * W_ + xc0) * 8);
                f16x8 c01 = *(const f16x8*)(xg + (yc0 * W_ + xc1) * 8);
                f16x8 c10 = *(const f16x8*)(xg + (yc1 * W_ + xc0) * 8);
                f16x8 c11 = *(const f16x8*)(xg + (yc1 * W_ + xc1) * 8);
                _Float16 h00 = (_Float16)w00, h01 = (_Float16)w01;
                _Float16 h10 = (_Float16)w10, h11 = (_Float16)w11;
                f16x8 vv = c00 * h00 + c01 * h01 + c10 * h10 + c11 * h11;  // v_pk_fma_f16
                int chunk = k ^ (pxl & 15);
                *(f16x8*)(vlds + pxl * 256 + chunk * 16) = vv;
            }
        }
        __syncthreads();
        #pragma unroll
        for (int nt = 0; nt < 4; ++nt) {
            int row = nt * 16 + l16;
            int sw  = row & 15;
            #pragma unroll
            for (int s = 0; s < 3; ++s) {
                f16x8 bF = *(const f16x8*)(vlds + row * 256 + (((s << 2) + quad) ^ sw) * 16);
                acc[nt] = __builtin_amdgcn_mfma_f32_16x16x32_f16(aF[gl][s], bF, acc[nt], 0, 0, 0);
            }
        }
    }

    // ---- epilogue: transpose 64co x 64px through LDS, coalesced stores ----
    __syncthreads();
    float* vf = (float*)vlds;          // 64 x 64 fp32 = 16 KB
    #pragma unroll
    for (int r = 0; r < 4; ++r) {
        int o = wv * 16 + quad * 4 + r;
        #pragma unroll
        for (int nt = 0; nt < 4; ++nt) {
            int col = nt ^ quad;       // quad == (o>>2)&3
            vf[o * 64 + col * 16 + l16] = acc[nt][r];
        }
    }
    __syncthreads();
    _Float16* pb = partial + (((size_t)gq * 4 + b) * 64) * HW + hrow * 128 + ns * 64;
    #pragma unroll
    for (int it = 0; it < 4; ++it) {
        int slot = tid + it * 256;     // 64 o x 16 p4
        int o    = slot >> 4;
        int p4   = slot & 15;
        int col  = (p4 >> 2) ^ ((o >> 2) & 3);
        f32x4 v = *(const f32x4*)(vf + o * 64 + col * 16 + (p4 & 3) * 4);
        f16x4 hv;
        #pragma unroll
        for (int j = 0; j < 4; ++j) hv[j] = (_Float16)v[j];
        *(f16x4*)(pb + (size_t)o * HW + p4 * 4) = hv;
    }
}

// ---------------------------------------------------------------------------
// out = bias + sum of 4 fp16 partials.
// ---------------------------------------------------------------------------
__global__ __launch_bounds__(256)
void reduce_out(const _Float16* __restrict__ p, const float* __restrict__ bias,
                float* __restrict__ out) {
    const int i8 = (blockIdx.x * 256 + threadIdx.x) * 8;
    const int o  = (i8 >> 14) & 63;
    const float bv = bias[o];
    f16x8 a = *(const f16x8*)(p + i8);
    f16x8 b = *(const f16x8*)(p + i8 + 4194304);
    f16x8 c = *(const f16x8*)(p + i8 + 8388608);
    f16x8 d = *(const f16x8*)(p + i8 + 12582912);
    float t[8];
    #pragma unroll
    for (int j = 0; j < 8; ++j)
        t[j] = bv + (float)a[j] + (float)b[j] + (float)c[j] + (float)d[j];
    *(float4*)(out + i8)     = make_float4(t[0], t[1], t[2], t[3]);
    *(float4*)(out + i8 + 4) = make_float4(t[4], t[5], t[6], t[7]);
}

// ---------------------------------------------------------------------------
extern "C" void kernel_launch(void* const* d_in, const int* in_sizes, int n_in,
                              void* d_out, int out_size, void* d_ws, size_t ws_size,
                              hipStream_t stream) {
    const float* x  = (const float*)d_in[0];
    const float* ef = (const float*)d_in[1];
    const float* w1 = (const float*)d_in[2];
    const float* b1 = (const float*)d_in[3];
    const float* w2 = (const float*)d_in[4];
    const float* b2 = (const float*)d_in[5];
    const float* w3 = (const float*)d_in[6];
    const float* b3 = (const float*)d_in[7];
    const float* w4 = (const float*)d_in[8];
    const float* b4 = (const float*)d_in[9];
    const float* wd = (const float*)d_in[10];
    const float* bd = (const float*)d_in[11];
    float* out = (float*)d_out;

    char* ws = (char*)d_ws;
    _Float16* ef_t = (_Float16*)(ws);                     // 25,165,824 B
    _Float16* part = (_Float16*)(ws);                     // 33,554,432 B (deform phase, overlays ef_t+tA)
    _Float16* tA   = (_Float16*)(ws + 25165824);          //  8,388,608 B
    _Float16* tB   = (_Float16*)(ws + 33554432);          //  8,388,608 B
    _Float16* off2 = (_Float16*)(ws + 41943040);          // 37,748,736 B
    _Float16* mskb = (_Float16*)(ws + 79691776);          // 18,874,368 B
    _Float16* wpd  = (_Float16*)(ws + 98566144);          //    196,608 B
    _Float16* A1   = (_Float16*)(ws + 98762752);          //    221,184 B
    _Float16* A2   = (_Float16*)(ws + 98983936);          //     73,728 B
    _Float16* A3   = (_Float16*)(ws + 99057664);          //     73,728 B
    _Float16* A4   = (_Float16*)(ws + 99131392);          //    589,824 B
    _Float16* xtb  = (_Float16*)(ws + 99721216);          // 16,777,216 B -> ends 116,498,432 (same as R6)

    prep_all<<<6864, 256, 0, stream>>>(wd, w1, w2, w3, w4, x, ef,
                                       wpd, A1, A2, A3, A4, xtb, ef_t);

    conv_mfma<192, 64, 2, 2, 2, 4, 1><<<dim3(512, 1), 256, 0, stream>>>(ef_t, A1, b1, tA, nullptr);
    conv_mfma< 64, 64, 2, 2, 2, 4, 1><<<dim3(512, 1), 256, 0, stream>>>(tA, A2, b2, tB, nullptr);
    conv_mfma< 64, 64, 2, 2, 2, 4, 1><<<dim3(512, 1), 256, 0, stream>>>(tB, A3, b3, tA, nullptr);
    conv_mfma< 64, 512, 2, 2, 4, 4, 2><<<dim3(512, 4), 256, 0, stream>>>(tA, A4, b4, off2, mskb);

    deform_mfma<<<4096, 256, 0, stream>>>(xtb, off2, mskb, wpd, part);
    reduce_out<<<2048, 256, 0, stream>>>(part, bd, out);
}